// Round 9
// baseline (625.671 us; speedup 1.0000x reference)
//
#include <hip/hip_runtime.h>
#include <cstdint>
#include <cstddef>

// All external tensors are FP32 (per reference). Internals use bf16 for MFMA.
typedef unsigned short u16;
typedef __attribute__((ext_vector_type(4))) float f32x4;
typedef __attribute__((ext_vector_type(8))) __bf16 bf16x8;
typedef __attribute__((ext_vector_type(4))) __bf16 bf16x4;
typedef __attribute__((ext_vector_type(8))) unsigned short u16x8;
typedef __attribute__((ext_vector_type(4))) unsigned short u16x4;

#define DEV static __device__ __forceinline__

#if __has_builtin(__builtin_amdgcn_exp2f)
#define EXP2(x) __builtin_amdgcn_exp2f(x)
#else
#define EXP2(x) exp2f(x)
#endif

DEV float bf2f(u16 v) { return __uint_as_float(((unsigned)v) << 16); }
DEV u16 f2bf(float f) {
  unsigned u = __float_as_uint(f);
  return (u16)((u + 0x7FFFu + ((u >> 16) & 1u)) >> 16);
}

DEV void gl_lds16(const void* g, void* l) {
  __builtin_amdgcn_global_load_lds((const __attribute__((address_space(1))) void*)g,
                                   (__attribute__((address_space(3))) void*)l, 16, 0, 0);
}

// ---------------------------------------------------------------------------
// 64x64 tiled transpose + fp32->bf16 cast: out[c][r] = bf16(in[r][c]).
__global__ __launch_bounds__(256) void transpose64(const float* __restrict__ in,
                                                   u16* __restrict__ out, int incols) {
  __shared__ __attribute__((aligned(16))) u16 t[64 * 72];
  const int r0 = blockIdx.x * 64, c0 = blockIdx.y * 64, tid = threadIdx.x;
#pragma unroll
  for (int i = 0; i < 2; i++) {
    int c = i * 256 + tid;
    int row = c >> 3, cc = c & 7;
    const float* src = &in[(size_t)(r0 + row) * incols + c0 + cc * 8];
    f32x4 v0 = *(const f32x4*)src;
    f32x4 v1 = *(const f32x4*)(src + 4);
    u16x8 o;
#pragma unroll
    for (int j = 0; j < 4; j++) { o[j] = f2bf(v0[j]); o[4 + j] = f2bf(v1[j]); }
    *(u16x8*)&t[row * 72 + cc * 8] = o;
  }
  __syncthreads();
#pragma unroll
  for (int i = 0; i < 2; i++) {
    int c = i * 256 + tid;
    int d = c >> 3, nc = c & 7;
    u16x8 o;
#pragma unroll
    for (int j = 0; j < 8; j++) o[j] = t[(nc * 8 + j) * 72 + d];
    *(u16x8*)&out[(size_t)(c0 + d) * 1024 + r0 + nc * 8] = o;
  }
}

// ---------------------------------------------------------------------------
// LayerNorm over DIM=1024 (fp32 in, bf16 out), one block per row.
__global__ __launch_bounds__(256) void ln_x(const float* __restrict__ x,
                                            const float* __restrict__ sc,
                                            const float* __restrict__ bi,
                                            u16* __restrict__ xn) {
  __shared__ float red[8];
  const int row = blockIdx.x, tid = threadIdx.x;
  const int w = tid >> 6;
  f32x4 f = *(const f32x4*)&x[(size_t)row * 1024 + tid * 4];
  float s = f[0] + f[1] + f[2] + f[3];
  float q = f[0] * f[0] + f[1] * f[1] + f[2] * f[2] + f[3] * f[3];
#pragma unroll
  for (int off = 1; off < 64; off <<= 1) {
    s += __shfl_xor(s, off);
    q += __shfl_xor(q, off);
  }
  if ((tid & 63) == 0) { red[w] = s; red[4 + w] = q; }
  __syncthreads();
  float S = red[0] + red[1] + red[2] + red[3];
  float Q = red[4] + red[5] + red[6] + red[7];
  float mu = S * (1.0f / 1024.0f);
  float var = Q * (1.0f / 1024.0f) - mu * mu;
  float rs = rsqrtf(var + 1e-6f);
  f32x4 scv = *(const f32x4*)&sc[tid * 4];
  f32x4 biv = *(const f32x4*)&bi[tid * 4];
  u16* o = xn + (size_t)row * 1024 + tid * 4;
#pragma unroll
  for (int j = 0; j < 4; j++) o[j] = f2bf((f[j] - mu) * rs * scv[j] + biv[j]);
}

// ---------------------------------------------------------------------------
// C[M][N] = A[M][K] * Bt[N][K]^T, bf16 in; out bf16 or fp32 (F32OUT).
// 128x128 tile, BK=64, XOR-swizzled LDS -> <=2-way conflicts.
template <bool F32OUT>
__global__ __launch_bounds__(256) void gemm_bt(const u16* __restrict__ A,
                                               const u16* __restrict__ Bt,
                                               void* __restrict__ Cp,
                                               int M, int N, int K) {
  __shared__ __attribute__((aligned(16))) u16 Als[128 * 64];
  __shared__ __attribute__((aligned(16))) u16 Bls[128 * 64];
  const int tid = threadIdx.x;
  const int w = tid >> 6, lane = tid & 63, ln = lane & 15, quad = lane >> 4;
  const int m0 = blockIdx.y * 128, n0 = blockIdx.x * 128;
  const int moff = (w & 1) * 64, noff = (w >> 1) * 64;
  const f32x4 fzero = {0.f, 0.f, 0.f, 0.f};
  f32x4 acc[4][4];
#pragma unroll
  for (int i = 0; i < 4; i++)
#pragma unroll
    for (int j = 0; j < 4; j++) acc[i][j] = fzero;

  const u16* aS[4];
  const u16* bS[4];
#pragma unroll
  for (int i = 0; i < 4; i++) {
    int s = i * 256 + tid;
    int row = s >> 3, cs = (s & 7) ^ (row & 7);
    aS[i] = A + (size_t)(m0 + row) * K + cs * 8;
    bS[i] = Bt + (size_t)(n0 + row) * K + cs * 8;
  }

  for (int k0 = 0; k0 < K; k0 += 64) {
    __syncthreads();
#pragma unroll
    for (int i = 0; i < 4; i++) {
      int s = i * 256 + tid;
      gl_lds16(aS[i] + k0, &Als[s * 8]);
      gl_lds16(bS[i] + k0, &Bls[s * 8]);
    }
    __syncthreads();
#pragma unroll
    for (int kk = 0; kk < 2; kk++) {
      bf16x8 af[4], bfv[4];
#pragma unroll
      for (int mi = 0; mi < 4; mi++)
        af[mi] = *(const bf16x8*)
            &Als[(moff + mi * 16 + ln) * 64 + (((kk * 4 + quad) ^ (ln & 7)) * 8)];
#pragma unroll
      for (int ni = 0; ni < 4; ni++)
        bfv[ni] = *(const bf16x8*)
            &Bls[(noff + ni * 16 + ln) * 64 + (((kk * 4 + quad) ^ (ln & 7)) * 8)];
#pragma unroll
      for (int mi = 0; mi < 4; mi++)
#pragma unroll
        for (int ni = 0; ni < 4; ni++)
          acc[mi][ni] = __builtin_amdgcn_mfma_f32_16x16x32_bf16(af[mi], bfv[ni],
                                                                acc[mi][ni], 0, 0, 0);
    }
  }
#pragma unroll
  for (int mi = 0; mi < 4; mi++)
#pragma unroll
    for (int ni = 0; ni < 4; ni++)
#pragma unroll
      for (int r = 0; r < 4; r++) {
        size_t m = m0 + moff + mi * 16 + quad * 4 + r;
        size_t n = n0 + noff + ni * 16 + ln;
        if (F32OUT)
          ((float*)Cp)[m * N + n] = acc[mi][ni][r];
        else
          ((u16*)Cp)[m * N + n] = f2bf(acc[mi][ni][r]);
      }
}

// ---------------------------------------------------------------------------
// QKV GEMM with FUSED per-head LayerNorm epilogue (round-8, verified).
// M=8192, N=1536, K=1024. Columns: [0,1024) Q-heads (LN+SCL -> Q layout),
// [1024,1280) K-groups (LN -> Kb layout), [1280,1536) V (raw bf16 ->
// compact Vraw[8192][256]).
__global__ __launch_bounds__(256) void gemm_qkv(const u16* __restrict__ A,
                                                const u16* __restrict__ Bt,
                                                const float* __restrict__ qs,
                                                const float* __restrict__ qb,
                                                const float* __restrict__ ks,
                                                const float* __restrict__ kb,
                                                u16* __restrict__ Qout,
                                                u16* __restrict__ Kout,
                                                u16* __restrict__ Vraw) {
  const int M = 8192, N = 1536, K = 1024;
  (void)M; (void)N;
  __shared__ __attribute__((aligned(16))) u16 Als[128 * 64];
  __shared__ __attribute__((aligned(16))) u16 Bls[128 * 64];
  const int tid = threadIdx.x;
  const int w = tid >> 6, lane = tid & 63, ln = lane & 15, quad = lane >> 4;
  const int m0 = blockIdx.y * 128, n0 = blockIdx.x * 128;
  const int moff = (w & 1) * 64, noff = (w >> 1) * 64;
  const f32x4 fzero = {0.f, 0.f, 0.f, 0.f};
  f32x4 acc[4][4];
#pragma unroll
  for (int i = 0; i < 4; i++)
#pragma unroll
    for (int j = 0; j < 4; j++) acc[i][j] = fzero;

  const u16* aS[4];
  const u16* bS[4];
#pragma unroll
  for (int i = 0; i < 4; i++) {
    int s = i * 256 + tid;
    int row = s >> 3, cs = (s & 7) ^ (row & 7);
    aS[i] = A + (size_t)(m0 + row) * K + cs * 8;
    bS[i] = Bt + (size_t)(n0 + row) * K + cs * 8;
  }

  for (int k0 = 0; k0 < K; k0 += 64) {
    __syncthreads();
#pragma unroll
    for (int i = 0; i < 4; i++) {
      int s = i * 256 + tid;
      gl_lds16(aS[i] + k0, &Als[s * 8]);
      gl_lds16(bS[i] + k0, &Bls[s * 8]);
    }
    __syncthreads();
#pragma unroll
    for (int kk = 0; kk < 2; kk++) {
      bf16x8 af[4], bfv[4];
#pragma unroll
      for (int mi = 0; mi < 4; mi++)
        af[mi] = *(const bf16x8*)
            &Als[(moff + mi * 16 + ln) * 64 + (((kk * 4 + quad) ^ (ln & 7)) * 8)];
#pragma unroll
      for (int ni = 0; ni < 4; ni++)
        bfv[ni] = *(const bf16x8*)
            &Bls[(noff + ni * 16 + ln) * 64 + (((kk * 4 + quad) ^ (ln & 7)) * 8)];
#pragma unroll
      for (int mi = 0; mi < 4; mi++)
#pragma unroll
        for (int ni = 0; ni < 4; ni++)
          acc[mi][ni] = __builtin_amdgcn_mfma_f32_16x16x32_bf16(af[mi], bfv[ni],
                                                                acc[mi][ni], 0, 0, 0);
    }
  }

  // -------- fused epilogue --------
  const int nb = n0 + noff;  // 64-aligned head/group slice base (wave-uniform)
  if (nb < 1280) {
    const float SCL = 0.18033688011112042f;  // 0.125 * log2(e)
    const bool isQ = (nb < 1024);
    const float* scp = isQ ? qs : ks;
    const float* bip = isQ ? qb : kb;
    const float mul = isQ ? SCL : 1.0f;
    float scl[4], bia[4];
#pragma unroll
    for (int ni = 0; ni < 4; ni++) {
      scl[ni] = scp[ni * 16 + ln];
      bia[ni] = bip[ni * 16 + ln];
    }
#pragma unroll
    for (int mi = 0; mi < 4; mi++)
#pragma unroll
      for (int r = 0; r < 4; r++) {
        const int m = m0 + moff + mi * 16 + quad * 4 + r;
        const int bidx = m >> 11, nseq = m & 2047;
        float v0 = acc[mi][0][r], v1 = acc[mi][1][r];
        float v2 = acc[mi][2][r], v3 = acc[mi][3][r];
        float s = (v0 + v1) + (v2 + v3);
        float q2 = (v0 * v0 + v1 * v1) + (v2 * v2 + v3 * v3);
#pragma unroll
        for (int off = 1; off < 16; off <<= 1) {
          s += __shfl_xor(s, off);
          q2 += __shfl_xor(q2, off);
        }
        const float mu = s * (1.0f / 64.0f);
        const float var = q2 * (1.0f / 64.0f) - mu * mu;
        const float rs = rsqrtf(var + 1e-6f);
        u16* op;
        if (isQ) {
          const int h = nb >> 6;
          op = Qout + ((size_t)(bidx * 16 + h) * 2048 + nseq) * 64;
        } else {
          const int g = (nb - 1024) >> 6;
          op = Kout + ((size_t)(bidx * 4 + g) * 2048 + nseq) * 64;
        }
        op[0 * 16 + ln] = f2bf(((v0 - mu) * rs * scl[0] + bia[0]) * mul);
        op[1 * 16 + ln] = f2bf(((v1 - mu) * rs * scl[1] + bia[1]) * mul);
        op[2 * 16 + ln] = f2bf(((v2 - mu) * rs * scl[2] + bia[2]) * mul);
        op[3 * 16 + ln] = f2bf(((v3 - mu) * rs * scl[3] + bia[3]) * mul);
      }
  } else {
    const int g2 = nb - 1280;  // 0,64,128,192
#pragma unroll
    for (int mi = 0; mi < 4; mi++)
#pragma unroll
      for (int r = 0; r < 4; r++) {
        const int m = m0 + moff + mi * 16 + quad * 4 + r;
        u16* op = Vraw + (size_t)m * 256 + g2;
#pragma unroll
        for (int ni = 0; ni < 4; ni++) op[ni * 16 + ln] = f2bf(acc[mi][ni][r]);
      }
  }
}

// ---------------------------------------------------------------------------
// V transpose: Vraw[8192][256] -> Vt [b][g][64][2048]. grid = (32, 16).
// Keys PERMUTED within each 64-key tile (PV A-operand = one 16B chunk/lane):
//   key kappa = 32c + quad*4 + u*16 + v  ->  pos p = 32c + quad*8 + u*4 + v
__global__ __launch_bounds__(256) void vtrans(const u16* __restrict__ Vraw,
                                              u16* __restrict__ Vt) {
  __shared__ __attribute__((aligned(16))) u16 t[64 * 72];
  const int n0 = blockIdx.x * 64;
  const int bg = blockIdx.y;
  const int b = bg >> 2, g = bg & 3;
  const int tid = threadIdx.x;
  const u16* src = Vraw + (size_t)(b * 2048 + n0) * 256 + g * 64;
#pragma unroll
  for (int i = 0; i < 2; i++) {
    int c = i * 256 + tid;
    int row = c >> 3, cc = c & 7;
    *(f32x4*)&t[row * 72 + cc * 8] = *(const f32x4*)&src[(size_t)row * 256 + cc * 8];
  }
  __syncthreads();
  u16* dst = Vt + (size_t)bg * 64 * 2048 + n0;
#pragma unroll
  for (int i = 0; i < 2; i++) {
    int c = i * 256 + tid;
    int d = c >> 3, nc = c & 7;
    const int pA = 32 * (nc >> 2) + (nc & 1) * 16 + ((nc >> 1) & 1) * 4;
    u16x8 o;
#pragma unroll
    for (int j = 0; j < 8; j++) o[j] = t[(nc * 8 + j) * 72 + d];
    u16x4 lo = {o[0], o[1], o[2], o[3]};
    u16x4 hi = {o[4], o[5], o[6], o[7]};
    *(u16x4*)&dst[(size_t)d * 2048 + pA] = lo;
    *(u16x4*)&dst[(size_t)d * 2048 + pA + 8] = hi;
  }
}

// ---------------------------------------------------------------------------
// Flash attention, transposed-S, fixed-max softmax, KT=64 keys/iter.
//
// Round-9: KEY-SPLIT WAVES. Round-7's 2-wave config ran at ~2x the MFMA
// floor: 2 waves/SIMD alternating a serial ds_read->QK->exp2->PV chain.
// Grid is stuck at 4 blocks/CU (1024 blocks / 256 CU) and per-wave q-rows
// can't grow (VGPRs). Fix: 4 waves/block = (q-half qh) x (key-half kh).
// Each wave: 64 q-rows x 32 keys/iter — half of round-7's work, and reads
// only ITS half of the K/V tiles, so per-CU LDS traffic / MFMA / exp2
// totals are UNCHANGED while resident waves double (8->16/CU, 2->4/SIMD).
// (Round-2's regression was different: its 4 waves each read the FULL tile.)
// One-time epilogue: kh=0 waves dump partial O/rsum to LDS (reusing the
// dead K/V buffers +2KB), kh=1 waves add, divide, store.
// Loop body per wave is round-7's verified code with chunk c fixed = kh.
// launch_bounds(256,4): cap 128 VGPR; round-7's identical loop measured 112.
__global__ __launch_bounds__(256, 4) void attn(const u16* __restrict__ Q,
                                               const u16* __restrict__ Kb,
                                               const u16* __restrict__ Vt,
                                               u16* __restrict__ Out) {
  __shared__ __attribute__((aligned(16))) char smem[34816];
  u16* const Kls0 = (u16*)smem;                // 8KB [key][d] (swizzled chunks)
  u16* const Kls1 = (u16*)(smem + 8192);
  u16* const Vls0 = (u16*)(smem + 16384);      // 8KB [d][key-permuted]
  u16* const Vls1 = (u16*)(smem + 24576);
  const int qt = blockIdx.x;
  const int bh = blockIdx.y;
  const int b = bh >> 4, h = bh & 15, g = h >> 2;
  const int tid = threadIdx.x, w = tid >> 6, lane = tid & 63;
  const int ln = lane & 15, quad = lane >> 4;
  const int qh = w >> 1;  // q-row half owned by this wave
  const int kh = w & 1;   // key half owned by this wave
  const u16* Qg = Q + ((size_t)(b * 16 + h) * 2048 + qt * 128 + qh * 64) * 64;
  const u16* Kg = Kb + (size_t)(b * 4 + g) * 2048 * 64;
  const u16* Vg = Vt + (size_t)(b * 4 + g) * 64 * 2048;
  const f32x4 fzero = {0.f, 0.f, 0.f, 0.f};

  // Q fragments (B-operand): rows m = mi*16+ln, k(d) = ks2*32 + quad*8
  bf16x8 qf[4][2];
#pragma unroll
  for (int mi = 0; mi < 4; mi++)
#pragma unroll
    for (int ks2 = 0; ks2 < 2; ks2++)
      qf[mi][ks2] = *(const bf16x8*)&Qg[(size_t)(mi * 16 + ln) * 64 + ks2 * 32 + quad * 8];

  f32x4 oacc[4][4];  // [ni(d-tile)][mi(m-tile)] — partial over this wave's keys
#pragma unroll
  for (int ni = 0; ni < 4; ni++)
#pragma unroll
    for (int mi = 0; mi < 4; mi++) oacc[ni][mi] = fzero;
  f32x4 rsum[4];  // partial row sums (MFMA ones-trick)
#pragma unroll
  for (int mi = 0; mi < 4; mi++) rsum[mi] = fzero;
  bf16x8 vones;
#pragma unroll
  for (int j = 0; j < 8; j++) vones[j] = (__bf16)1.0f;

  // staging geometry: 2 K-chunks + 2 V-chunks per thread (256 threads)
  int krow[2], kcs[2];
#pragma unroll
  for (int i = 0; i < 2; i++) {
    int s = i * 256 + tid;
    krow[i] = s >> 3;
    kcs[i] = (s & 7) ^ (krow[i] & 7);
  }

  auto STAGE = [&](int kt, u16* Kd, u16* Vd) {
#pragma unroll
    for (int i = 0; i < 2; i++) {
      int s = i * 256 + tid;
      gl_lds16(Kg + (size_t)(kt * 64 + krow[i]) * 64 + kcs[i] * 8, &Kd[s * 8]);
      gl_lds16(Vg + (size_t)krow[i] * 2048 + kt * 64 + kcs[i] * 8, &Vd[s * 8]);
    }
  };

  auto BODY = [&](int kt, const u16* K_, const u16* V_, u16* Kn, u16* Vn) {
    if (kt + 1 < 32) STAGE(kt + 1, Kn, Vn);  // prefetch, in flight during compute

    // this wave's 32-key chunk = keys kh*32 + [0,32)
    bf16x8 kf[2][2];  // [ni(key-16-tile)][kstep(d half)]
#pragma unroll
    for (int ni = 0; ni < 2; ni++) {
      const int kr = (kh * 32 + ni * 16 + ln) * 64;
      kf[ni][0] = *(const bf16x8*)&K_[kr + ((quad ^ (ln & 7)) * 8)];
      kf[ni][1] = *(const bf16x8*)&K_[kr + (((4 + quad) ^ (ln & 7)) * 8)];
    }

    // S^T: sacc[mi][ni][r] = S[key=kh*32+ni*16+quad*4+r][m=mi*16+ln]
    f32x4 sacc[4][2];
    __builtin_amdgcn_s_setprio(1);
#pragma unroll
    for (int ni = 0; ni < 2; ni++)
#pragma unroll
      for (int mi = 0; mi < 4; mi++) {
        f32x4 tt = __builtin_amdgcn_mfma_f32_16x16x32_bf16(kf[ni][0], qf[mi][0],
                                                           fzero, 0, 0, 0);
        sacc[mi][ni] = __builtin_amdgcn_mfma_f32_16x16x32_bf16(kf[ni][1], qf[mi][1],
                                                               tt, 0, 0, 0);
      }
    __builtin_amdgcn_s_setprio(0);

    // fixed-max softmax: p = exp2(s), packed straight into PV B-fragments.
    bf16x8 pfa[4];
#pragma unroll
    for (int mi = 0; mi < 4; mi++) {
      pfa[mi][0] = (__bf16)EXP2(sacc[mi][0][0]);
      pfa[mi][1] = (__bf16)EXP2(sacc[mi][0][1]);
      pfa[mi][2] = (__bf16)EXP2(sacc[mi][0][2]);
      pfa[mi][3] = (__bf16)EXP2(sacc[mi][0][3]);
      pfa[mi][4] = (__bf16)EXP2(sacc[mi][1][0]);
      pfa[mi][5] = (__bf16)EXP2(sacc[mi][1][1]);
      pfa[mi][6] = (__bf16)EXP2(sacc[mi][1][2]);
      pfa[mi][7] = (__bf16)EXP2(sacc[mi][1][3]);
    }

    // partial row sums on the matrix pipe
#pragma unroll
    for (int mi = 0; mi < 4; mi++)
      rsum[mi] = __builtin_amdgcn_mfma_f32_16x16x32_bf16(vones, pfa[mi],
                                                         rsum[mi], 0, 0, 0);

    // O^T += Vt * P^T over this wave's keys (permuted-V chunk kh*4+quad)
#pragma unroll
    for (int ni = 0; ni < 4; ni++) {
      bf16x8 vf = *(const bf16x8*)
          &V_[(ni * 16 + ln) * 64 + (((4 * kh + quad) ^ (ln & 7)) * 8)];
      __builtin_amdgcn_s_setprio(1);
#pragma unroll
      for (int mi = 0; mi < 4; mi++)
        oacc[ni][mi] = __builtin_amdgcn_mfma_f32_16x16x32_bf16(vf, pfa[mi],
                                                               oacc[ni][mi], 0, 0, 0);
      __builtin_amdgcn_s_setprio(0);
    }
    __syncthreads();  // drains prefetch vmcnt; all waves done reading K_/V_
  };

  STAGE(0, Kls0, Vls0);
  __syncthreads();
  for (int kt = 0; kt < 32; kt += 2) {
    BODY(kt, Kls0, Vls0, Kls1, Vls1);
    BODY(kt + 1, Kls1, Vls1, Kls0, Vls0);
  }

  // ---- cross-wave combine (kh=0 partials + kh=1 partials) ----
  // K/V buffers are dead; reuse [0,32K) for oacc dumps, [32K,34K) for rsum.
  // Layout: conflict-free 16B/lane: od[qh][ni*4+mi][lane] (f32x4 each).
  float* const od = (float*)smem;
  float* const rd = (float*)(smem + 32768);
  if (kh == 0) {
    float* myo = od + qh * 4096;
#pragma unroll
    for (int ni = 0; ni < 4; ni++)
#pragma unroll
      for (int mi = 0; mi < 4; mi++)
        *(f32x4*)&myo[(ni * 4 + mi) * 256 + lane * 4] = oacc[ni][mi];
    f32x4 rv = {rsum[0][0], rsum[1][0], rsum[2][0], rsum[3][0]};
    *(f32x4*)&rd[qh * 256 + lane * 4] = rv;
  }
  __syncthreads();
  if (kh == 1) {
    const float* po = od + qh * 4096;
    f32x4 rv = *(const f32x4*)&rd[qh * 256 + lane * 4];
#pragma unroll
    for (int mi = 0; mi < 4; mi++) {
      float inv = 1.0f / (rsum[mi][0] + rv[mi]);
      u16* Og = Out + ((size_t)b * 2048 + qt * 128 + qh * 64 + mi * 16 + ln) * 1024 + h * 64;
#pragma unroll
      for (int ni = 0; ni < 4; ni++) {
        f32x4 p = *(const f32x4*)&po[(ni * 4 + mi) * 256 + lane * 4];
        bf16x4 ov = {(__bf16)((oacc[ni][mi][0] + p[0]) * inv),
                     (__bf16)((oacc[ni][mi][1] + p[1]) * inv),
                     (__bf16)((oacc[ni][mi][2] + p[2]) * inv),
                     (__bf16)((oacc[ni][mi][3] + p[3]) * inv)};
        *(bf16x4*)&Og[ni * 16 + quad * 4] = ov;
      }
    }
  }
}

// ---------------------------------------------------------------------------
extern "C" void kernel_launch(void* const* d_in, const int* in_sizes, int n_in,
                              void* d_out, int out_size, void* d_ws, size_t ws_size,
                              hipStream_t stream) {
  const float* x    = (const float*)d_in[0];
  const float* lns  = (const float*)d_in[1];
  const float* lnb  = (const float*)d_in[2];
  const float* Wq   = (const float*)d_in[3];
  const float* Wkv  = (const float*)d_in[4];
  const float* qns  = (const float*)d_in[5];
  const float* qnb  = (const float*)d_in[6];
  const float* kns  = (const float*)d_in[7];
  const float* knb  = (const float*)d_in[8];
  const float* Wout = (const float*)d_in[9];
  float* out = (float*)d_out;
  char* ws = (char*)d_ws;

  // Workspace map (47 MB total):
  const size_t o_xn = 0;                   // 16 MB: xn (bf16); later aout
  const size_t o_q  = 16777216;            // 16 MB: Q [b][h][n][d]
  const size_t o_vr = o_q + 16777216;      // 4 MB: Vraw [8192][256]
  const size_t o_bt = o_vr + 4194304;      // 3 MB: W^T (bf16), reused for Wout^T
  const size_t o_k  = o_bt + 3145728;      // 4 MB: Kbuf [b][g][n][d]
  const size_t o_vt = o_k + 4194304;       // 4 MB: Vt [b][g][d][n] (key-permuted)
  u16* xn   = (u16*)(ws + o_xn);
  u16* Qbuf = (u16*)(ws + o_q);
  u16* Vraw = (u16*)(ws + o_vr);
  u16* bt   = (u16*)(ws + o_bt);
  u16* Kbuf = (u16*)(ws + o_k);
  u16* Vtb  = (u16*)(ws + o_vt);
  u16* aout = xn;  // xn dead after gemm_qkv; attn output fits exactly (16 MiB)

  transpose64<<<dim3(16, 16), 256, 0, stream>>>(Wq, bt, 1024);
  transpose64<<<dim3(16, 8), 256, 0, stream>>>(Wkv, bt + 1024 * 1024, 512);
  ln_x<<<8192, 256, 0, stream>>>(x, lns, lnb, xn);
  gemm_qkv<<<dim3(12, 64), 256, 0, stream>>>(xn, bt, qns, qnb, kns, knb,
                                             Qbuf, Kbuf, Vraw);
  transpose64<<<dim3(16, 16), 256, 0, stream>>>(Wout, bt, 1024);
  vtrans<<<dim3(32, 16), 256, 0, stream>>>(Vraw, Vtb);
  attn<<<dim3(16, 64), 256, 0, stream>>>(Qbuf, Kbuf, Vtb, aout);
  gemm_bt<true><<<dim3(8, 64), 256, 0, stream>>>(aout, bt, out, 8192, 1024, 1024);

  (void)in_sizes; (void)n_in; (void)out_size; (void)ws_size;
}

// Round 10
// 242.744 us; speedup vs baseline: 2.5775x; 2.5775x over previous
//
#include <hip/hip_runtime.h>
#include <cstdint>
#include <cstddef>

// All external tensors are FP32 (per reference). Internals use bf16 for MFMA.
typedef unsigned short u16;
typedef __attribute__((ext_vector_type(4))) float f32x4;
typedef __attribute__((ext_vector_type(8))) __bf16 bf16x8;
typedef __attribute__((ext_vector_type(4))) __bf16 bf16x4;
typedef __attribute__((ext_vector_type(8))) unsigned short u16x8;
typedef __attribute__((ext_vector_type(4))) unsigned short u16x4;

#define DEV static __device__ __forceinline__

#if __has_builtin(__builtin_amdgcn_exp2f)
#define EXP2(x) __builtin_amdgcn_exp2f(x)
#else
#define EXP2(x) exp2f(x)
#endif

DEV float bf2f(u16 v) { return __uint_as_float(((unsigned)v) << 16); }
DEV u16 f2bf(float f) {
  unsigned u = __float_as_uint(f);
  return (u16)((u + 0x7FFFu + ((u >> 16) & 1u)) >> 16);
}

DEV void gl_lds16(const void* g, void* l) {
  __builtin_amdgcn_global_load_lds((const __attribute__((address_space(1))) void*)g,
                                   (__attribute__((address_space(3))) void*)l, 16, 0, 0);
}

// ---------------------------------------------------------------------------
// Round-10: MERGED prep kernel — ln_x + the three 64x64 weight transposes in
// ONE launch (8 -> 5 kernel launches total; diagnostic for launch-gap cost).
// Flat grid: [0,8192) = ln_x rows; [8192,8448) = Wq^T; [8448,8576) = Wkv^T;
// [8576,8832) = Wout^T (own 2MB region btW — can no longer reuse btQ since
// it now runs BEFORE gemm_qkv). Branch is block-uniform; all paths 256 thr.
__global__ __launch_bounds__(256) void prep(const float* __restrict__ x,
                                            const float* __restrict__ lns,
                                            const float* __restrict__ lnb,
                                            const float* __restrict__ Wq,
                                            const float* __restrict__ Wkv,
                                            const float* __restrict__ Wout,
                                            u16* __restrict__ xn,
                                            u16* __restrict__ btQ,
                                            u16* __restrict__ btKV,
                                            u16* __restrict__ btW) {
  __shared__ __attribute__((aligned(16))) u16 t[64 * 72];
  __shared__ float red[8];
  const int bid = blockIdx.x, tid = threadIdx.x;

  if (bid < 8192) {
    // ---- LayerNorm over DIM=1024 (fp32 in, bf16 out), one block per row ----
    const int row = bid, w = tid >> 6;
    f32x4 f = *(const f32x4*)&x[(size_t)row * 1024 + tid * 4];
    float s = f[0] + f[1] + f[2] + f[3];
    float q = f[0] * f[0] + f[1] * f[1] + f[2] * f[2] + f[3] * f[3];
#pragma unroll
    for (int off = 1; off < 64; off <<= 1) {
      s += __shfl_xor(s, off);
      q += __shfl_xor(q, off);
    }
    if ((tid & 63) == 0) { red[w] = s; red[4 + w] = q; }
    __syncthreads();
    float S = red[0] + red[1] + red[2] + red[3];
    float Q = red[4] + red[5] + red[6] + red[7];
    float mu = S * (1.0f / 1024.0f);
    float var = Q * (1.0f / 1024.0f) - mu * mu;
    float rs = rsqrtf(var + 1e-6f);
    f32x4 scv = *(const f32x4*)&lns[tid * 4];
    f32x4 biv = *(const f32x4*)&lnb[tid * 4];
    u16* o = xn + (size_t)row * 1024 + tid * 4;
#pragma unroll
    for (int j = 0; j < 4; j++) o[j] = f2bf((f[j] - mu) * rs * scv[j] + biv[j]);
    return;
  }

  // ---- 64x64 tiled transpose + fp32->bf16 cast: out[c][r] = bf16(in[r][c]) ----
  int tt = bid - 8192;
  const float* in;
  u16* out;
  int incols;
  if (tt < 256) {
    in = Wq; out = btQ; incols = 1024;
  } else if (tt < 384) {
    tt -= 256; in = Wkv; out = btKV; incols = 512;
  } else {
    tt -= 384; in = Wout; out = btW; incols = 1024;
  }
  const int r0 = (tt & 15) * 64, c0 = (tt >> 4) * 64;
#pragma unroll
  for (int i = 0; i < 2; i++) {
    int c = i * 256 + tid;
    int row = c >> 3, cc = c & 7;
    const float* src = &in[(size_t)(r0 + row) * incols + c0 + cc * 8];
    f32x4 v0 = *(const f32x4*)src;
    f32x4 v1 = *(const f32x4*)(src + 4);
    u16x8 o;
#pragma unroll
    for (int j = 0; j < 4; j++) { o[j] = f2bf(v0[j]); o[4 + j] = f2bf(v1[j]); }
    *(u16x8*)&t[row * 72 + cc * 8] = o;
  }
  __syncthreads();
#pragma unroll
  for (int i = 0; i < 2; i++) {
    int c = i * 256 + tid;
    int d = c >> 3, nc = c & 7;
    u16x8 o;
#pragma unroll
    for (int j = 0; j < 8; j++) o[j] = t[(nc * 8 + j) * 72 + d];
    *(u16x8*)&out[(size_t)(c0 + d) * 1024 + r0 + nc * 8] = o;
  }
}

// ---------------------------------------------------------------------------
// C[M][N] = A[M][K] * Bt[N][K]^T, bf16 in; out bf16 or fp32 (F32OUT).
// 128x128 tile, BK=64, XOR-swizzled LDS -> <=2-way conflicts.
template <bool F32OUT>
__global__ __launch_bounds__(256) void gemm_bt(const u16* __restrict__ A,
                                               const u16* __restrict__ Bt,
                                               void* __restrict__ Cp,
                                               int M, int N, int K) {
  __shared__ __attribute__((aligned(16))) u16 Als[128 * 64];
  __shared__ __attribute__((aligned(16))) u16 Bls[128 * 64];
  const int tid = threadIdx.x;
  const int w = tid >> 6, lane = tid & 63, ln = lane & 15, quad = lane >> 4;
  const int m0 = blockIdx.y * 128, n0 = blockIdx.x * 128;
  const int moff = (w & 1) * 64, noff = (w >> 1) * 64;
  const f32x4 fzero = {0.f, 0.f, 0.f, 0.f};
  f32x4 acc[4][4];
#pragma unroll
  for (int i = 0; i < 4; i++)
#pragma unroll
    for (int j = 0; j < 4; j++) acc[i][j] = fzero;

  const u16* aS[4];
  const u16* bS[4];
#pragma unroll
  for (int i = 0; i < 4; i++) {
    int s = i * 256 + tid;
    int row = s >> 3, cs = (s & 7) ^ (row & 7);
    aS[i] = A + (size_t)(m0 + row) * K + cs * 8;
    bS[i] = Bt + (size_t)(n0 + row) * K + cs * 8;
  }

  for (int k0 = 0; k0 < K; k0 += 64) {
    __syncthreads();
#pragma unroll
    for (int i = 0; i < 4; i++) {
      int s = i * 256 + tid;
      gl_lds16(aS[i] + k0, &Als[s * 8]);
      gl_lds16(bS[i] + k0, &Bls[s * 8]);
    }
    __syncthreads();
#pragma unroll
    for (int kk = 0; kk < 2; kk++) {
      bf16x8 af[4], bfv[4];
#pragma unroll
      for (int mi = 0; mi < 4; mi++)
        af[mi] = *(const bf16x8*)
            &Als[(moff + mi * 16 + ln) * 64 + (((kk * 4 + quad) ^ (ln & 7)) * 8)];
#pragma unroll
      for (int ni = 0; ni < 4; ni++)
        bfv[ni] = *(const bf16x8*)
            &Bls[(noff + ni * 16 + ln) * 64 + (((kk * 4 + quad) ^ (ln & 7)) * 8)];
#pragma unroll
      for (int mi = 0; mi < 4; mi++)
#pragma unroll
        for (int ni = 0; ni < 4; ni++)
          acc[mi][ni] = __builtin_amdgcn_mfma_f32_16x16x32_bf16(af[mi], bfv[ni],
                                                                acc[mi][ni], 0, 0, 0);
    }
  }
#pragma unroll
  for (int mi = 0; mi < 4; mi++)
#pragma unroll
    for (int ni = 0; ni < 4; ni++)
#pragma unroll
      for (int r = 0; r < 4; r++) {
        size_t m = m0 + moff + mi * 16 + quad * 4 + r;
        size_t n = n0 + noff + ni * 16 + ln;
        if (F32OUT)
          ((float*)Cp)[m * N + n] = acc[mi][ni][r];
        else
          ((u16*)Cp)[m * N + n] = f2bf(acc[mi][ni][r]);
      }
}

// ---------------------------------------------------------------------------
// QKV GEMM with FUSED per-head LayerNorm epilogue (round-8, verified).
// M=8192, N=1536, K=1024. Columns: [0,1024) Q-heads (LN+SCL -> Q layout),
// [1024,1280) K-groups (LN -> Kb layout), [1280,1536) V (raw bf16 ->
// compact Vraw[8192][256]).
__global__ __launch_bounds__(256) void gemm_qkv(const u16* __restrict__ A,
                                                const u16* __restrict__ Bt,
                                                const float* __restrict__ qs,
                                                const float* __restrict__ qb,
                                                const float* __restrict__ ks,
                                                const float* __restrict__ kb,
                                                u16* __restrict__ Qout,
                                                u16* __restrict__ Kout,
                                                u16* __restrict__ Vraw) {
  const int K = 1024;
  __shared__ __attribute__((aligned(16))) u16 Als[128 * 64];
  __shared__ __attribute__((aligned(16))) u16 Bls[128 * 64];
  const int tid = threadIdx.x;
  const int w = tid >> 6, lane = tid & 63, ln = lane & 15, quad = lane >> 4;
  const int m0 = blockIdx.y * 128, n0 = blockIdx.x * 128;
  const int moff = (w & 1) * 64, noff = (w >> 1) * 64;
  const f32x4 fzero = {0.f, 0.f, 0.f, 0.f};
  f32x4 acc[4][4];
#pragma unroll
  for (int i = 0; i < 4; i++)
#pragma unroll
    for (int j = 0; j < 4; j++) acc[i][j] = fzero;

  const u16* aS[4];
  const u16* bS[4];
#pragma unroll
  for (int i = 0; i < 4; i++) {
    int s = i * 256 + tid;
    int row = s >> 3, cs = (s & 7) ^ (row & 7);
    aS[i] = A + (size_t)(m0 + row) * K + cs * 8;
    bS[i] = Bt + (size_t)(n0 + row) * K + cs * 8;
  }

  for (int k0 = 0; k0 < K; k0 += 64) {
    __syncthreads();
#pragma unroll
    for (int i = 0; i < 4; i++) {
      int s = i * 256 + tid;
      gl_lds16(aS[i] + k0, &Als[s * 8]);
      gl_lds16(bS[i] + k0, &Bls[s * 8]);
    }
    __syncthreads();
#pragma unroll
    for (int kk = 0; kk < 2; kk++) {
      bf16x8 af[4], bfv[4];
#pragma unroll
      for (int mi = 0; mi < 4; mi++)
        af[mi] = *(const bf16x8*)
            &Als[(moff + mi * 16 + ln) * 64 + (((kk * 4 + quad) ^ (ln & 7)) * 8)];
#pragma unroll
      for (int ni = 0; ni < 4; ni++)
        bfv[ni] = *(const bf16x8*)
            &Bls[(noff + ni * 16 + ln) * 64 + (((kk * 4 + quad) ^ (ln & 7)) * 8)];
#pragma unroll
      for (int mi = 0; mi < 4; mi++)
#pragma unroll
        for (int ni = 0; ni < 4; ni++)
          acc[mi][ni] = __builtin_amdgcn_mfma_f32_16x16x32_bf16(af[mi], bfv[ni],
                                                                acc[mi][ni], 0, 0, 0);
    }
  }

  // -------- fused epilogue --------
  const int nb = n0 + noff;  // 64-aligned head/group slice base (wave-uniform)
  if (nb < 1280) {
    const float SCL = 0.18033688011112042f;  // 0.125 * log2(e)
    const bool isQ = (nb < 1024);
    const float* scp = isQ ? qs : ks;
    const float* bip = isQ ? qb : kb;
    const float mul = isQ ? SCL : 1.0f;
    float scl[4], bia[4];
#pragma unroll
    for (int ni = 0; ni < 4; ni++) {
      scl[ni] = scp[ni * 16 + ln];
      bia[ni] = bip[ni * 16 + ln];
    }
#pragma unroll
    for (int mi = 0; mi < 4; mi++)
#pragma unroll
      for (int r = 0; r < 4; r++) {
        const int m = m0 + moff + mi * 16 + quad * 4 + r;
        const int bidx = m >> 11, nseq = m & 2047;
        float v0 = acc[mi][0][r], v1 = acc[mi][1][r];
        float v2 = acc[mi][2][r], v3 = acc[mi][3][r];
        float s = (v0 + v1) + (v2 + v3);
        float q2 = (v0 * v0 + v1 * v1) + (v2 * v2 + v3 * v3);
#pragma unroll
        for (int off = 1; off < 16; off <<= 1) {
          s += __shfl_xor(s, off);
          q2 += __shfl_xor(q2, off);
        }
        const float mu = s * (1.0f / 64.0f);
        const float var = q2 * (1.0f / 64.0f) - mu * mu;
        const float rs = rsqrtf(var + 1e-6f);
        u16* op;
        if (isQ) {
          const int h = nb >> 6;
          op = Qout + ((size_t)(bidx * 16 + h) * 2048 + nseq) * 64;
        } else {
          const int g = (nb - 1024) >> 6;
          op = Kout + ((size_t)(bidx * 4 + g) * 2048 + nseq) * 64;
        }
        op[0 * 16 + ln] = f2bf(((v0 - mu) * rs * scl[0] + bia[0]) * mul);
        op[1 * 16 + ln] = f2bf(((v1 - mu) * rs * scl[1] + bia[1]) * mul);
        op[2 * 16 + ln] = f2bf(((v2 - mu) * rs * scl[2] + bia[2]) * mul);
        op[3 * 16 + ln] = f2bf(((v3 - mu) * rs * scl[3] + bia[3]) * mul);
      }
  } else {
    const int g2 = nb - 1280;  // 0,64,128,192
#pragma unroll
    for (int mi = 0; mi < 4; mi++)
#pragma unroll
      for (int r = 0; r < 4; r++) {
        const int m = m0 + moff + mi * 16 + quad * 4 + r;
        u16* op = Vraw + (size_t)m * 256 + g2;
#pragma unroll
        for (int ni = 0; ni < 4; ni++) op[ni * 16 + ln] = f2bf(acc[mi][ni][r]);
      }
  }
}

// ---------------------------------------------------------------------------
// V transpose: Vraw[8192][256] -> Vt [b][g][64][2048]. grid = (32, 16).
// Keys PERMUTED within each 64-key tile (PV A-operand = one 16B chunk/lane):
//   key kappa = 32c + quad*4 + u*16 + v  ->  pos p = 32c + quad*8 + u*4 + v
__global__ __launch_bounds__(256) void vtrans(const u16* __restrict__ Vraw,
                                              u16* __restrict__ Vt) {
  __shared__ __attribute__((aligned(16))) u16 t[64 * 72];
  const int n0 = blockIdx.x * 64;
  const int bg = blockIdx.y;
  const int b = bg >> 2, g = bg & 3;
  const int tid = threadIdx.x;
  const u16* src = Vraw + (size_t)(b * 2048 + n0) * 256 + g * 64;
#pragma unroll
  for (int i = 0; i < 2; i++) {
    int c = i * 256 + tid;
    int row = c >> 3, cc = c & 7;
    *(f32x4*)&t[row * 72 + cc * 8] = *(const f32x4*)&src[(size_t)row * 256 + cc * 8];
  }
  __syncthreads();
  u16* dst = Vt + (size_t)bg * 64 * 2048 + n0;
#pragma unroll
  for (int i = 0; i < 2; i++) {
    int c = i * 256 + tid;
    int d = c >> 3, nc = c & 7;
    const int pA = 32 * (nc >> 2) + (nc & 1) * 16 + ((nc >> 1) & 1) * 4;
    u16x8 o;
#pragma unroll
    for (int j = 0; j < 8; j++) o[j] = t[(nc * 8 + j) * 72 + d];
    u16x4 lo = {o[0], o[1], o[2], o[3]};
    u16x4 hi = {o[4], o[5], o[6], o[7]};
    *(u16x4*)&dst[(size_t)d * 2048 + pA] = lo;
    *(u16x4*)&dst[(size_t)d * 2048 + pA + 8] = hi;
  }
}

// ---------------------------------------------------------------------------
// Flash attention, transposed-S, fixed-max softmax, KT=64 keys/iter.
// Round-7 verified 76.5us: 128-thr blocks, 2 waves x 64 q-rows, grid (16,64),
// LDS K/V dbuf, one barrier/kt, lane-local P, permuted-V b128 PV reads,
// 0 bank conflicts, rsum via all-ones MFMA, launch_bounds(128,2). UNCHANGED.
// (Round-5/9 lesson, twice-measured: a 64q x 64d wave needs ~150 VGPR; any
// 128-VGPR cap => catastrophic spill. Do not re-cap.)
__global__ __launch_bounds__(128, 2) void attn(const u16* __restrict__ Q,
                                               const u16* __restrict__ Kb,
                                               const u16* __restrict__ Vt,
                                               u16* __restrict__ Out) {
  __shared__ __attribute__((aligned(16))) u16 Kls0[64 * 64];
  __shared__ __attribute__((aligned(16))) u16 Kls1[64 * 64];
  __shared__ __attribute__((aligned(16))) u16 Vls0[64 * 64];
  __shared__ __attribute__((aligned(16))) u16 Vls1[64 * 64];
  const int qt = blockIdx.x;
  const int bh = blockIdx.y;
  const int b = bh >> 4, h = bh & 15, g = h >> 2;
  const int tid = threadIdx.x, w = tid >> 6, lane = tid & 63;
  const int ln = lane & 15, quad = lane >> 4;
  const u16* Qg = Q + ((size_t)(b * 16 + h) * 2048 + qt * 128 + w * 64) * 64;
  const u16* Kg = Kb + (size_t)(b * 4 + g) * 2048 * 64;
  const u16* Vg = Vt + (size_t)(b * 4 + g) * 64 * 2048;
  const f32x4 fzero = {0.f, 0.f, 0.f, 0.f};

  bf16x8 qf[4][2];
#pragma unroll
  for (int mi = 0; mi < 4; mi++)
#pragma unroll
    for (int ks2 = 0; ks2 < 2; ks2++)
      qf[mi][ks2] = *(const bf16x8*)&Qg[(size_t)(mi * 16 + ln) * 64 + ks2 * 32 + quad * 8];

  f32x4 oacc[4][4];
#pragma unroll
  for (int ni = 0; ni < 4; ni++)
#pragma unroll
    for (int mi = 0; mi < 4; mi++) oacc[ni][mi] = fzero;
  f32x4 rsum[4];
#pragma unroll
  for (int mi = 0; mi < 4; mi++) rsum[mi] = fzero;
  bf16x8 vones;
#pragma unroll
  for (int j = 0; j < 8; j++) vones[j] = (__bf16)1.0f;

  int krow[4], kcs[4];
#pragma unroll
  for (int i = 0; i < 4; i++) {
    int s = i * 128 + tid;
    krow[i] = s >> 3;
    kcs[i] = (s & 7) ^ (krow[i] & 7);
  }

  auto STAGE = [&](int kt, u16* Kd, u16* Vd) {
#pragma unroll
    for (int i = 0; i < 4; i++) {
      int s = i * 128 + tid;
      gl_lds16(Kg + (size_t)(kt * 64 + krow[i]) * 64 + kcs[i] * 8, &Kd[s * 8]);
      gl_lds16(Vg + (size_t)krow[i] * 2048 + kt * 64 + kcs[i] * 8, &Vd[s * 8]);
    }
  };

  auto BODY = [&](int kt, const u16* K_, const u16* V_, u16* Kn, u16* Vn) {
    if (kt + 1 < 32) STAGE(kt + 1, Kn, Vn);

#pragma unroll
    for (int c = 0; c < 2; c++) {
      bf16x8 kf[2][2];
#pragma unroll
      for (int ni = 0; ni < 2; ni++) {
        const int kr = (c * 32 + ni * 16 + ln) * 64;
        kf[ni][0] = *(const bf16x8*)&K_[kr + ((quad ^ (ln & 7)) * 8)];
        kf[ni][1] = *(const bf16x8*)&K_[kr + (((4 + quad) ^ (ln & 7)) * 8)];
      }

      f32x4 sacc[4][2];
      __builtin_amdgcn_s_setprio(1);
#pragma unroll
      for (int ni = 0; ni < 2; ni++)
#pragma unroll
        for (int mi = 0; mi < 4; mi++) {
          f32x4 tt = __builtin_amdgcn_mfma_f32_16x16x32_bf16(kf[ni][0], qf[mi][0],
                                                             fzero, 0, 0, 0);
          sacc[mi][ni] = __builtin_amdgcn_mfma_f32_16x16x32_bf16(kf[ni][1], qf[mi][1],
                                                                 tt, 0, 0, 0);
        }
      __builtin_amdgcn_s_setprio(0);

      bf16x8 pfa[4];
#pragma unroll
      for (int mi = 0; mi < 4; mi++) {
        pfa[mi][0] = (__bf16)EXP2(sacc[mi][0][0]);
        pfa[mi][1] = (__bf16)EXP2(sacc[mi][0][1]);
        pfa[mi][2] = (__bf16)EXP2(sacc[mi][0][2]);
        pfa[mi][3] = (__bf16)EXP2(sacc[mi][0][3]);
        pfa[mi][4] = (__bf16)EXP2(sacc[mi][1][0]);
        pfa[mi][5] = (__bf16)EXP2(sacc[mi][1][1]);
        pfa[mi][6] = (__bf16)EXP2(sacc[mi][1][2]);
        pfa[mi][7] = (__bf16)EXP2(sacc[mi][1][3]);
      }

#pragma unroll
      for (int mi = 0; mi < 4; mi++)
        rsum[mi] = __builtin_amdgcn_mfma_f32_16x16x32_bf16(vones, pfa[mi],
                                                           rsum[mi], 0, 0, 0);

#pragma unroll
      for (int ni = 0; ni < 4; ni++) {
        bf16x8 vf = *(const bf16x8*)
            &V_[(ni * 16 + ln) * 64 + (((4 * c + quad) ^ (ln & 7)) * 8)];
        __builtin_amdgcn_s_setprio(1);
#pragma unroll
        for (int mi = 0; mi < 4; mi++)
          oacc[ni][mi] = __builtin_amdgcn_mfma_f32_16x16x32_bf16(vf, pfa[mi],
                                                                 oacc[ni][mi], 0, 0, 0);
        __builtin_amdgcn_s_setprio(0);
      }
    }
    __syncthreads();
  };

  STAGE(0, Kls0, Vls0);
  __syncthreads();
  for (int kt = 0; kt < 32; kt += 2) {
    BODY(kt, Kls0, Vls0, Kls1, Vls1);
    BODY(kt + 1, Kls1, Vls1, Kls0, Vls0);
  }

#pragma unroll
  for (int mi = 0; mi < 4; mi++) {
    float inv = 1.0f / rsum[mi][0];
    u16* Og = Out + ((size_t)b * 2048 + qt * 128 + w * 64 + mi * 16 + ln) * 1024 + h * 64;
#pragma unroll
    for (int ni = 0; ni < 4; ni++) {
      bf16x4 ov = {(__bf16)(oacc[ni][mi][0] * inv), (__bf16)(oacc[ni][mi][1] * inv),
                   (__bf16)(oacc[ni][mi][2] * inv), (__bf16)(oacc[ni][mi][3] * inv)};
      *(bf16x4*)&Og[ni * 16 + quad * 4] = ov;
    }
  }
}

// ---------------------------------------------------------------------------
extern "C" void kernel_launch(void* const* d_in, const int* in_sizes, int n_in,
                              void* d_out, int out_size, void* d_ws, size_t ws_size,
                              hipStream_t stream) {
  const float* x    = (const float*)d_in[0];
  const float* lns  = (const float*)d_in[1];
  const float* lnb  = (const float*)d_in[2];
  const float* Wq   = (const float*)d_in[3];
  const float* Wkv  = (const float*)d_in[4];
  const float* qns  = (const float*)d_in[5];
  const float* qnb  = (const float*)d_in[6];
  const float* kns  = (const float*)d_in[7];
  const float* knb  = (const float*)d_in[8];
  const float* Wout = (const float*)d_in[9];
  float* out = (float*)d_out;
  char* ws = (char*)d_ws;

  // Workspace map (49 MB total; Wout^T now has its own region since prep
  // runs all transposes up-front):
  const size_t o_xn  = 0;                   // 16 MB: xn (bf16); later aout
  const size_t o_q   = 16777216;            // 16 MB: Q [b][h][n][d]
  const size_t o_vr  = o_q + 16777216;      // 4 MB: Vraw [8192][256]
  const size_t o_bt  = o_vr + 4194304;      // 3 MB: Wq^T (2MB) + Wkv^T (1MB)
  const size_t o_btw = o_bt + 3145728;      // 2 MB: Wout^T
  const size_t o_k   = o_btw + 2097152;     // 4 MB: Kbuf [b][g][n][d]
  const size_t o_vt  = o_k + 4194304;       // 4 MB: Vt [b][g][d][n] (key-permuted)
  u16* xn   = (u16*)(ws + o_xn);
  u16* Qbuf = (u16*)(ws + o_q);
  u16* Vraw = (u16*)(ws + o_vr);
  u16* btQ  = (u16*)(ws + o_bt);
  u16* btKV = btQ + 1024 * 1024;
  u16* btW  = (u16*)(ws + o_btw);
  u16* Kbuf = (u16*)(ws + o_k);
  u16* Vtb  = (u16*)(ws + o_vt);
  u16* aout = xn;  // xn dead after gemm_qkv; attn output fits exactly (16 MiB)

  prep<<<8832, 256, 0, stream>>>(x, lns, lnb, Wq, Wkv, Wout, xn, btQ, btKV, btW);
  gemm_qkv<<<dim3(12, 64), 256, 0, stream>>>(xn, btQ, qns, qnb, kns, knb,
                                             Qbuf, Kbuf, Vraw);
  vtrans<<<dim3(32, 16), 256, 0, stream>>>(Vraw, Vtb);
  attn<<<dim3(16, 64), 128, 0, stream>>>(Qbuf, Kbuf, Vtb, aout);
  gemm_bt<true><<<dim3(8, 64), 256, 0, stream>>>(aout, btW, out, 8192, 1024, 1024);

  (void)in_sizes; (void)n_in; (void)out_size; (void)ws_size;
}

// Round 12
// 238.940 us; speedup vs baseline: 2.6185x; 1.0159x over previous
//
#include <hip/hip_runtime.h>
#include <cstdint>
#include <cstddef>

// All external tensors are FP32 (per reference). Internals use bf16 for MFMA.
typedef unsigned short u16;
typedef __attribute__((ext_vector_type(4))) float f32x4;
typedef __attribute__((ext_vector_type(8))) __bf16 bf16x8;
typedef __attribute__((ext_vector_type(4))) __bf16 bf16x4;
typedef __attribute__((ext_vector_type(8))) unsigned short u16x8;
typedef __attribute__((ext_vector_type(4))) unsigned short u16x4;

#define DEV static __device__ __forceinline__

#if __has_builtin(__builtin_amdgcn_exp2f)
#define EXP2(x) __builtin_amdgcn_exp2f(x)
#else
#define EXP2(x) exp2f(x)
#endif

DEV float bf2f(u16 v) { return __uint_as_float(((unsigned)v) << 16); }
DEV u16 f2bf(float f) {
  unsigned u = __float_as_uint(f);
  return (u16)((u + 0x7FFFu + ((u >> 16) & 1u)) >> 16);
}

DEV void gl_lds16(const void* g, void* l) {
  __builtin_amdgcn_global_load_lds((const __attribute__((address_space(1))) void*)g,
                                   (__attribute__((address_space(3))) void*)l, 16, 0, 0);
}

// XCD-aware bijective block swizzle (valid when nwg % 8 == 0): blocks with
// equal (orig & 7) land on the same XCD (dispatch round-robin) and receive
// CONSECUTIVE logical ids -> with bx-fastest decomposition, one XCD's blocks
// share the whole B panel (L2-resident) and walk A slowly.
DEV int xcd_swizzle(int orig, int nwg) {
  return (orig & 7) * (nwg >> 3) + (orig >> 3);
}

// ---------------------------------------------------------------------------
// Round-10 prep kernel (verified): ln_x + the three 64x64 weight transposes.
// Flat grid: [0,8192) = ln_x rows; [8192,8448) = Wq^T; [8448,8576) = Wkv^T;
// [8576,8832) = Wout^T.
__global__ __launch_bounds__(256) void prep(const float* __restrict__ x,
                                            const float* __restrict__ lns,
                                            const float* __restrict__ lnb,
                                            const float* __restrict__ Wq,
                                            const float* __restrict__ Wkv,
                                            const float* __restrict__ Wout,
                                            u16* __restrict__ xn,
                                            u16* __restrict__ btQ,
                                            u16* __restrict__ btKV,
                                            u16* __restrict__ btW) {
  __shared__ __attribute__((aligned(16))) u16 t[64 * 72];
  __shared__ float red[8];
  const int bid = blockIdx.x, tid = threadIdx.x;

  if (bid < 8192) {
    const int row = bid, w = tid >> 6;
    f32x4 f = *(const f32x4*)&x[(size_t)row * 1024 + tid * 4];
    float s = f[0] + f[1] + f[2] + f[3];
    float q = f[0] * f[0] + f[1] * f[1] + f[2] * f[2] + f[3] * f[3];
#pragma unroll
    for (int off = 1; off < 64; off <<= 1) {
      s += __shfl_xor(s, off);
      q += __shfl_xor(q, off);
    }
    if ((tid & 63) == 0) { red[w] = s; red[4 + w] = q; }
    __syncthreads();
    float S = red[0] + red[1] + red[2] + red[3];
    float Q = red[4] + red[5] + red[6] + red[7];
    float mu = S * (1.0f / 1024.0f);
    float var = Q * (1.0f / 1024.0f) - mu * mu;
    float rs = rsqrtf(var + 1e-6f);
    f32x4 scv = *(const f32x4*)&lns[tid * 4];
    f32x4 biv = *(const f32x4*)&lnb[tid * 4];
    u16* o = xn + (size_t)row * 1024 + tid * 4;
#pragma unroll
    for (int j = 0; j < 4; j++) o[j] = f2bf((f[j] - mu) * rs * scv[j] + biv[j]);
    return;
  }

  int tt = bid - 8192;
  const float* in;
  u16* out;
  int incols;
  if (tt < 256) {
    in = Wq; out = btQ; incols = 1024;
  } else if (tt < 384) {
    tt -= 256; in = Wkv; out = btKV; incols = 512;
  } else {
    tt -= 384; in = Wout; out = btW; incols = 1024;
  }
  const int r0 = (tt & 15) * 64, c0 = (tt >> 4) * 64;
#pragma unroll
  for (int i = 0; i < 2; i++) {
    int c = i * 256 + tid;
    int row = c >> 3, cc = c & 7;
    const float* src = &in[(size_t)(r0 + row) * incols + c0 + cc * 8];
    f32x4 v0 = *(const f32x4*)src;
    f32x4 v1 = *(const f32x4*)(src + 4);
    u16x8 o;
#pragma unroll
    for (int j = 0; j < 4; j++) { o[j] = f2bf(v0[j]); o[4 + j] = f2bf(v1[j]); }
    *(u16x8*)&t[row * 72 + cc * 8] = o;
  }
  __syncthreads();
#pragma unroll
  for (int i = 0; i < 2; i++) {
    int c = i * 256 + tid;
    int d = c >> 3, nc = c & 7;
    u16x8 o;
#pragma unroll
    for (int j = 0; j < 8; j++) o[j] = t[(nc * 8 + j) * 72 + d];
    *(u16x8*)&out[(size_t)(c0 + d) * 1024 + r0 + nc * 8] = o;
  }
}

// ---------------------------------------------------------------------------
// C[M][N] = A[M][K] * Bt[N][K]^T, bf16 in; out bf16 or fp32 (F32OUT).
// 128x128 tile, BK=64, XOR-swizzled LDS -> <=2-way conflicts.
// Round-11: 1-D grid + XCD swizzle, bx-fastest: each XCD's blocks cover all
// B-columns (B stays L2-resident, read ~once/XCD) x few A-row-panels.
template <bool F32OUT>
__global__ __launch_bounds__(256) void gemm_bt(const u16* __restrict__ A,
                                               const u16* __restrict__ Bt,
                                               void* __restrict__ Cp,
                                               int M, int N, int K) {
  __shared__ __attribute__((aligned(16))) u16 Als[128 * 64];
  __shared__ __attribute__((aligned(16))) u16 Bls[128 * 64];
  const int tid = threadIdx.x;
  const int w = tid >> 6, lane = tid & 63, ln = lane & 15, quad = lane >> 4;
  const int nbx = N >> 7;
  const int wg = xcd_swizzle(blockIdx.x, gridDim.x);
  const int m0 = (wg / nbx) * 128, n0 = (wg % nbx) * 128;
  const int moff = (w & 1) * 64, noff = (w >> 1) * 64;
  const f32x4 fzero = {0.f, 0.f, 0.f, 0.f};
  f32x4 acc[4][4];
#pragma unroll
  for (int i = 0; i < 4; i++)
#pragma unroll
    for (int j = 0; j < 4; j++) acc[i][j] = fzero;

  const u16* aS[4];
  const u16* bS[4];
#pragma unroll
  for (int i = 0; i < 4; i++) {
    int s = i * 256 + tid;
    int row = s >> 3, cs = (s & 7) ^ (row & 7);
    aS[i] = A + (size_t)(m0 + row) * K + cs * 8;
    bS[i] = Bt + (size_t)(n0 + row) * K + cs * 8;
  }

  for (int k0 = 0; k0 < K; k0 += 64) {
    __syncthreads();
#pragma unroll
    for (int i = 0; i < 4; i++) {
      int s = i * 256 + tid;
      gl_lds16(aS[i] + k0, &Als[s * 8]);
      gl_lds16(bS[i] + k0, &Bls[s * 8]);
    }
    __syncthreads();
#pragma unroll
    for (int kk = 0; kk < 2; kk++) {
      bf16x8 af[4], bfv[4];
#pragma unroll
      for (int mi = 0; mi < 4; mi++)
        af[mi] = *(const bf16x8*)
            &Als[(moff + mi * 16 + ln) * 64 + (((kk * 4 + quad) ^ (ln & 7)) * 8)];
#pragma unroll
      for (int ni = 0; ni < 4; ni++)
        bfv[ni] = *(const bf16x8*)
            &Bls[(noff + ni * 16 + ln) * 64 + (((kk * 4 + quad) ^ (ln & 7)) * 8)];
#pragma unroll
      for (int mi = 0; mi < 4; mi++)
#pragma unroll
        for (int ni = 0; ni < 4; ni++)
          acc[mi][ni] = __builtin_amdgcn_mfma_f32_16x16x32_bf16(af[mi], bfv[ni],
                                                                acc[mi][ni], 0, 0, 0);
    }
  }
#pragma unroll
  for (int mi = 0; mi < 4; mi++)
#pragma unroll
    for (int ni = 0; ni < 4; ni++)
#pragma unroll
      for (int r = 0; r < 4; r++) {
        size_t m = m0 + moff + mi * 16 + quad * 4 + r;
        size_t n = n0 + noff + ni * 16 + ln;
        if (F32OUT)
          ((float*)Cp)[m * N + n] = acc[mi][ni][r];
        else
          ((u16*)Cp)[m * N + n] = f2bf(acc[mi][ni][r]);
      }
}

// ---------------------------------------------------------------------------
// QKV GEMM with FUSED per-head LayerNorm epilogue (round-8, verified).
// M=8192, N=1536, K=1024. Columns: [0,1024) Q-heads (LN+SCL -> Q layout),
// [1024,1280) K-groups (LN -> Kb layout), [1280,1536) V (raw bf16 ->
// compact Vraw[8192][256]). Round-11: 1-D grid + XCD swizzle (bx-fastest).
__global__ __launch_bounds__(256) void gemm_qkv(const u16* __restrict__ A,
                                                const u16* __restrict__ Bt,
                                                const float* __restrict__ qs,
                                                const float* __restrict__ qb,
                                                const float* __restrict__ ks,
                                                const float* __restrict__ kb,
                                                u16* __restrict__ Qout,
                                                u16* __restrict__ Kout,
                                                u16* __restrict__ Vraw) {
  const int K = 1024;
  __shared__ __attribute__((aligned(16))) u16 Als[128 * 64];
  __shared__ __attribute__((aligned(16))) u16 Bls[128 * 64];
  const int tid = threadIdx.x;
  const int w = tid >> 6, lane = tid & 63, ln = lane & 15, quad = lane >> 4;
  const int wg = xcd_swizzle(blockIdx.x, gridDim.x);
  const int m0 = (wg / 12) * 128, n0 = (wg % 12) * 128;
  const int moff = (w & 1) * 64, noff = (w >> 1) * 64;
  const f32x4 fzero = {0.f, 0.f, 0.f, 0.f};
  f32x4 acc[4][4];
#pragma unroll
  for (int i = 0; i < 4; i++)
#pragma unroll
    for (int j = 0; j < 4; j++) acc[i][j] = fzero;

  const u16* aS[4];
  const u16* bS[4];
#pragma unroll
  for (int i = 0; i < 4; i++) {
    int s = i * 256 + tid;
    int row = s >> 3, cs = (s & 7) ^ (row & 7);
    aS[i] = A + (size_t)(m0 + row) * K + cs * 8;
    bS[i] = Bt + (size_t)(n0 + row) * K + cs * 8;
  }

  for (int k0 = 0; k0 < K; k0 += 64) {
    __syncthreads();
#pragma unroll
    for (int i = 0; i < 4; i++) {
      int s = i * 256 + tid;
      gl_lds16(aS[i] + k0, &Als[s * 8]);
      gl_lds16(bS[i] + k0, &Bls[s * 8]);
    }
    __syncthreads();
#pragma unroll
    for (int kk = 0; kk < 2; kk++) {
      bf16x8 af[4], bfv[4];
#pragma unroll
      for (int mi = 0; mi < 4; mi++)
        af[mi] = *(const bf16x8*)
            &Als[(moff + mi * 16 + ln) * 64 + (((kk * 4 + quad) ^ (ln & 7)) * 8)];
#pragma unroll
      for (int ni = 0; ni < 4; ni++)
        bfv[ni] = *(const bf16x8*)
            &Bls[(noff + ni * 16 + ln) * 64 + (((kk * 4 + quad) ^ (ln & 7)) * 8)];
#pragma unroll
      for (int mi = 0; mi < 4; mi++)
#pragma unroll
        for (int ni = 0; ni < 4; ni++)
          acc[mi][ni] = __builtin_amdgcn_mfma_f32_16x16x32_bf16(af[mi], bfv[ni],
                                                                acc[mi][ni], 0, 0, 0);
    }
  }

  // -------- fused epilogue --------
  const int nb = n0 + noff;  // 64-aligned head/group slice base (wave-uniform)
  if (nb < 1280) {
    const float SCL = 0.18033688011112042f;  // 0.125 * log2(e)
    const bool isQ = (nb < 1024);
    const float* scp = isQ ? qs : ks;
    const float* bip = isQ ? qb : kb;
    const float mul = isQ ? SCL : 1.0f;
    float scl[4], bia[4];
#pragma unroll
    for (int ni = 0; ni < 4; ni++) {
      scl[ni] = scp[ni * 16 + ln];
      bia[ni] = bip[ni * 16 + ln];
    }
#pragma unroll
    for (int mi = 0; mi < 4; mi++)
#pragma unroll
      for (int r = 0; r < 4; r++) {
        const int m = m0 + moff + mi * 16 + quad * 4 + r;
        const int bidx = m >> 11, nseq = m & 2047;
        float v0 = acc[mi][0][r], v1 = acc[mi][1][r];
        float v2 = acc[mi][2][r], v3 = acc[mi][3][r];
        float s = (v0 + v1) + (v2 + v3);
        float q2 = (v0 * v0 + v1 * v1) + (v2 * v2 + v3 * v3);
#pragma unroll
        for (int off = 1; off < 16; off <<= 1) {
          s += __shfl_xor(s, off);
          q2 += __shfl_xor(q2, off);
        }
        const float mu = s * (1.0f / 64.0f);
        const float var = q2 * (1.0f / 64.0f) - mu * mu;
        const float rs = rsqrtf(var + 1e-6f);
        u16* op;
        if (isQ) {
          const int h = nb >> 6;
          op = Qout + ((size_t)(bidx * 16 + h) * 2048 + nseq) * 64;
        } else {
          const int g = (nb - 1024) >> 6;
          op = Kout + ((size_t)(bidx * 4 + g) * 2048 + nseq) * 64;
        }
        op[0 * 16 + ln] = f2bf(((v0 - mu) * rs * scl[0] + bia[0]) * mul);
        op[1 * 16 + ln] = f2bf(((v1 - mu) * rs * scl[1] + bia[1]) * mul);
        op[2 * 16 + ln] = f2bf(((v2 - mu) * rs * scl[2] + bia[2]) * mul);
        op[3 * 16 + ln] = f2bf(((v3 - mu) * rs * scl[3] + bia[3]) * mul);
      }
  } else {
    const int g2 = nb - 1280;  // 0,64,128,192
#pragma unroll
    for (int mi = 0; mi < 4; mi++)
#pragma unroll
      for (int r = 0; r < 4; r++) {
        const int m = m0 + moff + mi * 16 + quad * 4 + r;
        u16* op = Vraw + (size_t)m * 256 + g2;
#pragma unroll
        for (int ni = 0; ni < 4; ni++) op[ni * 16 + ln] = f2bf(acc[mi][ni][r]);
      }
  }
}

// ---------------------------------------------------------------------------
// V transpose: Vraw[8192][256] -> Vt [b][g][64][2048]. grid = (32, 16).
// Keys PERMUTED within each 64-key tile (PV A-operand = one 16B chunk/lane):
//   key kappa = 32c + quad*4 + u*16 + v  ->  pos p = 32c + quad*8 + u*4 + v
__global__ __launch_bounds__(256) void vtrans(const u16* __restrict__ Vraw,
                                              u16* __restrict__ Vt) {
  __shared__ __attribute__((aligned(16))) u16 t[64 * 72];
  const int n0 = blockIdx.x * 64;
  const int bg = blockIdx.y;
  const int b = bg >> 2, g = bg & 3;
  const int tid = threadIdx.x;
  const u16* src = Vraw + (size_t)(b * 2048 + n0) * 256 + g * 64;
#pragma unroll
  for (int i = 0; i < 2; i++) {
    int c = i * 256 + tid;
    int row = c >> 3, cc = c & 7;
    *(f32x4*)&t[row * 72 + cc * 8] = *(const f32x4*)&src[(size_t)row * 256 + cc * 8];
  }
  __syncthreads();
  u16* dst = Vt + (size_t)bg * 64 * 2048 + n0;
#pragma unroll
  for (int i = 0; i < 2; i++) {
    int c = i * 256 + tid;
    int d = c >> 3, nc = c & 7;
    const int pA = 32 * (nc >> 2) + (nc & 1) * 16 + ((nc >> 1) & 1) * 4;
    u16x8 o;
#pragma unroll
    for (int j = 0; j < 8; j++) o[j] = t[(nc * 8 + j) * 72 + d];
    u16x4 lo = {o[0], o[1], o[2], o[3]};
    u16x4 hi = {o[4], o[5], o[6], o[7]};
    *(u16x4*)&dst[(size_t)d * 2048 + pA] = lo;
    *(u16x4*)&dst[(size_t)d * 2048 + pA + 8] = hi;
  }
}

// ---------------------------------------------------------------------------
// Flash attention, transposed-S, fixed-max softmax, KT=64 keys/iter.
// Round-7 verified 76.5us: 128-thr blocks, 2 waves x 64 q-rows, grid (16,64),
// LDS K/V dbuf, one barrier/kt, lane-local P, permuted-V b128 PV reads,
// 0 bank conflicts, rsum via all-ones MFMA, launch_bounds(128,2). UNCHANGED.
// (Round-5/9 lesson, twice-measured: a 64q x 64d wave needs ~150 VGPR; any
// 128-VGPR cap => catastrophic spill. Do not re-cap.)
__global__ __launch_bounds__(128, 2) void attn(const u16* __restrict__ Q,
                                               const u16* __restrict__ Kb,
                                               const u16* __restrict__ Vt,
                                               u16* __restrict__ Out) {
  __shared__ __attribute__((aligned(16))) u16 Kls0[64 * 64];
  __shared__ __attribute__((aligned(16))) u16 Kls1[64 * 64];
  __shared__ __attribute__((aligned(16))) u16 Vls0[64 * 64];
  __shared__ __attribute__((aligned(16))) u16 Vls1[64 * 64];
  const int qt = blockIdx.x;
  const int bh = blockIdx.y;
  const int b = bh >> 4, h = bh & 15, g = h >> 2;
  const int tid = threadIdx.x, w = tid >> 6, lane = tid & 63;
  const int ln = lane & 15, quad = lane >> 4;
  const u16* Qg = Q + ((size_t)(b * 16 + h) * 2048 + qt * 128 + w * 64) * 64;
  const u16* Kg = Kb + (size_t)(b * 4 + g) * 2048 * 64;
  const u16* Vg = Vt + (size_t)(b * 4 + g) * 64 * 2048;
  const f32x4 fzero = {0.f, 0.f, 0.f, 0.f};

  bf16x8 qf[4][2];
#pragma unroll
  for (int mi = 0; mi < 4; mi++)
#pragma unroll
    for (int ks2 = 0; ks2 < 2; ks2++)
      qf[mi][ks2] = *(const bf16x8*)&Qg[(size_t)(mi * 16 + ln) * 64 + ks2 * 32 + quad * 8];

  f32x4 oacc[4][4];
#pragma unroll
  for (int ni = 0; ni < 4; ni++)
#pragma unroll
    for (int mi = 0; mi < 4; mi++) oacc[ni][mi] = fzero;
  f32x4 rsum[4];
#pragma unroll
  for (int mi = 0; mi < 4; mi++) rsum[mi] = fzero;
  bf16x8 vones;
#pragma unroll
  for (int j = 0; j < 8; j++) vones[j] = (__bf16)1.0f;

  int krow[4], kcs[4];
#pragma unroll
  for (int i = 0; i < 4; i++) {
    int s = i * 128 + tid;
    krow[i] = s >> 3;
    kcs[i] = (s & 7) ^ (krow[i] & 7);
  }

  auto STAGE = [&](int kt, u16* Kd, u16* Vd) {
#pragma unroll
    for (int i = 0; i < 4; i++) {
      int s = i * 128 + tid;
      gl_lds16(Kg + (size_t)(kt * 64 + krow[i]) * 64 + kcs[i] * 8, &Kd[s * 8]);
      gl_lds16(Vg + (size_t)krow[i] * 2048 + kt * 64 + kcs[i] * 8, &Vd[s * 8]);
    }
  };

  auto BODY = [&](int kt, const u16* K_, const u16* V_, u16* Kn, u16* Vn) {
    if (kt + 1 < 32) STAGE(kt + 1, Kn, Vn);

#pragma unroll
    for (int c = 0; c < 2; c++) {
      bf16x8 kf[2][2];
#pragma unroll
      for (int ni = 0; ni < 2; ni++) {
        const int kr = (c * 32 + ni * 16 + ln) * 64;
        kf[ni][0] = *(const bf16x8*)&K_[kr + ((quad ^ (ln & 7)) * 8)];
        kf[ni][1] = *(const bf16x8*)&K_[kr + (((4 + quad) ^ (ln & 7)) * 8)];
      }

      f32x4 sacc[4][2];
      __builtin_amdgcn_s_setprio(1);
#pragma unroll
      for (int ni = 0; ni < 2; ni++)
#pragma unroll
        for (int mi = 0; mi < 4; mi++) {
          f32x4 tt = __builtin_amdgcn_mfma_f32_16x16x32_bf16(kf[ni][0], qf[mi][0],
                                                             fzero, 0, 0, 0);
          sacc[mi][ni] = __builtin_amdgcn_mfma_f32_16x16x32_bf16(kf[ni][1], qf[mi][1],
                                                                 tt, 0, 0, 0);
        }
      __builtin_amdgcn_s_setprio(0);

      bf16x8 pfa[4];
#pragma unroll
      for (int mi = 0; mi < 4; mi++) {
        pfa[mi][0] = (__bf16)EXP2(sacc[mi][0][0]);
        pfa[mi][1] = (__bf16)EXP2(sacc[mi][0][1]);
        pfa[mi][2] = (__bf16)EXP2(sacc[mi][0][2]);
        pfa[mi][3] = (__bf16)EXP2(sacc[mi][0][3]);
        pfa[mi][4] = (__bf16)EXP2(sacc[mi][1][0]);
        pfa[mi][5] = (__bf16)EXP2(sacc[mi][1][1]);
        pfa[mi][6] = (__bf16)EXP2(sacc[mi][1][2]);
        pfa[mi][7] = (__bf16)EXP2(sacc[mi][1][3]);
      }

#pragma unroll
      for (int mi = 0; mi < 4; mi++)
        rsum[mi] = __builtin_amdgcn_mfma_f32_16x16x32_bf16(vones, pfa[mi],
                                                           rsum[mi], 0, 0, 0);

#pragma unroll
      for (int ni = 0; ni < 4; ni++) {
        bf16x8 vf = *(const bf16x8*)
            &V_[(ni * 16 + ln) * 64 + (((4 * c + quad) ^ (ln & 7)) * 8)];
        __builtin_amdgcn_s_setprio(1);
#pragma unroll
        for (int mi = 0; mi < 4; mi++)
          oacc[ni][mi] = __builtin_amdgcn_mfma_f32_16x16x32_bf16(vf, pfa[mi],
                                                                 oacc[ni][mi], 0, 0, 0);
        __builtin_amdgcn_s_setprio(0);
      }
    }
    __syncthreads();
  };

  STAGE(0, Kls0, Vls0);
  __syncthreads();
  for (int kt = 0; kt < 32; kt += 2) {
    BODY(kt, Kls0, Vls0, Kls1, Vls1);
    BODY(kt + 1, Kls1, Vls1, Kls0, Vls0);
  }

#pragma unroll
  for (int mi = 0; mi < 4; mi++) {
    float inv = 1.0f / rsum[mi][0];
    u16* Og = Out + ((size_t)b * 2048 + qt * 128 + w * 64 + mi * 16 + ln) * 1024 + h * 64;
#pragma unroll
    for (int ni = 0; ni < 4; ni++) {
      bf16x4 ov = {(__bf16)(oacc[ni][mi][0] * inv), (__bf16)(oacc[ni][mi][1] * inv),
                   (__bf16)(oacc[ni][mi][2] * inv), (__bf16)(oacc[ni][mi][3] * inv)};
      *(bf16x4*)&Og[ni * 16 + quad * 4] = ov;
    }
  }
}

// ---------------------------------------------------------------------------
extern "C" void kernel_launch(void* const* d_in, const int* in_sizes, int n_in,
                              void* d_out, int out_size, void* d_ws, size_t ws_size,
                              hipStream_t stream) {
  const float* x    = (const float*)d_in[0];
  const float* lns  = (const float*)d_in[1];
  const float* lnb  = (const float*)d_in[2];
  const float* Wq   = (const float*)d_in[3];
  const float* Wkv  = (const float*)d_in[4];
  const float* qns  = (const float*)d_in[5];
  const float* qnb  = (const float*)d_in[6];
  const float* kns  = (const float*)d_in[7];
  const float* knb  = (const float*)d_in[8];
  const float* Wout = (const float*)d_in[9];
  float* out = (float*)d_out;
  char* ws = (char*)d_ws;

  // Workspace map (49 MB total):
  const size_t o_xn  = 0;                   // 16 MB: xn (bf16); later aout
  const size_t o_q   = 16777216;            // 16 MB: Q [b][h][n][d]
  const size_t o_vr  = o_q + 16777216;      // 4 MB: Vraw [8192][256]
  const size_t o_bt  = o_vr + 4194304;      // 3 MB: Wq^T (2MB) + Wkv^T (1MB)
  const size_t o_btw = o_bt + 3145728;      // 2 MB: Wout^T
  const size_t o_k   = o_btw + 2097152;     // 4 MB: Kbuf [b][g][n][d]
  const size_t o_vt  = o_k + 4194304;       // 4 MB: Vt [b][g][d][n] (key-permuted)
  u16* xn   = (u16*)(ws + o_xn);
  u16* Qbuf = (u16*)(ws + o_q);
  u16* Vraw = (u16*)(ws + o_vr);
  u16* btQ  = (u16*)(ws + o_bt);
  u16* btKV = btQ + 1024 * 1024;
  u16* btW  = (u16*)(ws + o_btw);
  u16* Kbuf = (u16*)(ws + o_k);
  u16* Vtb  = (u16*)(ws + o_vt);
  u16* aout = xn;  // xn dead after gemm_qkv; attn output fits exactly (16 MiB)

  prep<<<8832, 256, 0, stream>>>(x, lns, lnb, Wq, Wkv, Wout, xn, btQ, btKV, btW);
  gemm_qkv<<<768, 256, 0, stream>>>(xn, btQ, qns, qnb, kns, knb,
                                    Qbuf, Kbuf, Vraw);
  vtrans<<<dim3(32, 16), 256, 0, stream>>>(Vraw, Vtb);
  attn<<<dim3(16, 64), 128, 0, stream>>>(Qbuf, Kbuf, Vtb, aout);
  gemm_bt<true><<<512, 256, 0, stream>>>(aout, btW, out, 8192, 1024, 1024);

  (void)in_sizes; (void)n_in; (void)out_size; (void)ws_size;
}